// Round 1
// baseline (501.936 us; speedup 1.0000x reference)
//
#include <hip/hip_runtime.h>
#include <math.h>

// Problem constants (fixed by the reference)
#define NQ   1024      // B*LT
#define DIM  512
#define NH   8
#define DHD  64
#define DFF  2048
#define LM   64        // LMEM
#define KPAD 516       // padded LDS row stride (floats) to break 512-stride bank conflicts

// ---------------------------------------------------------------- helpers
__device__ __forceinline__ float blk_sum(float v, volatile float* red) {
#pragma unroll
    for (int o = 32; o; o >>= 1) v += __shfl_down(v, o);
    __syncthreads();                       // protect red reuse across calls
    if ((threadIdx.x & 63) == 0) red[threadIdx.x >> 6] = v;
    __syncthreads();
    return red[0] + red[1] + red[2] + red[3];
}

// ------------------------------------------------- K1: LN(dec_output) + argmax
__global__ __launch_bounds__(256) void ln0_argmax_k(
    const float* __restrict__ dec_out, const float* __restrict__ attn_out,
    const float* __restrict__ g, const float* __restrict__ be,
    float* __restrict__ x, int* __restrict__ samples)
{
    __shared__ float red[4];
    __shared__ float rv[4]; __shared__ int ri[4];
    const int n = blockIdx.x, t = threadIdx.x;

    float2 v = ((const float2*)(dec_out + (size_t)n * DIM))[t];
    float mu  = blk_sum(v.x + v.y, red) * (1.f / DIM);
    float dx = v.x - mu, dy = v.y - mu;
    float var = blk_sum(dx * dx + dy * dy, red) * (1.f / DIM);
    float rs = rsqrtf(var + 1e-5f);
    float2 gg = ((const float2*)g)[t], bb = ((const float2*)be)[t];
    ((float2*)(x + (size_t)n * DIM))[t] =
        make_float2(dx * rs * gg.x + bb.x, dy * rs * gg.y + bb.y);

    // argmax over 1025 entries, first-occurrence semantics
    const float* ar = attn_out + (size_t)n * 1025;
    float bv = -INFINITY; int bi = 0x7fffffff;
    for (int i = t; i < 1025; i += 256) {
        float val = ar[i];
        if (val > bv || (val == bv && i < bi)) { bv = val; bi = i; }
    }
#pragma unroll
    for (int o = 32; o; o >>= 1) {
        float ov = __shfl_down(bv, o); int oi = __shfl_down(bi, o);
        if (ov > bv || (ov == bv && oi < bi)) { bv = ov; bi = oi; }
    }
    if ((t & 63) == 0) { rv[t >> 6] = bv; ri[t >> 6] = bi; }
    __syncthreads();
    if (t == 0) {
#pragma unroll
        for (int w = 1; w < 4; ++w)
            if (rv[w] > bv || (rv[w] == bv && ri[w] < bi)) { bv = rv[w]; bi = ri[w]; }
        samples[n] = bi - 1;
    }
}

// ------------------------------------------------- transpose 512x512 (Wk -> WkT)
__global__ __launch_bounds__(256) void transpose512_k(
    const float* __restrict__ in, float* __restrict__ out)
{
    __shared__ float tile[32][33];
    const int bx = blockIdx.x * 32, by = blockIdx.y * 32;
    const int tx = threadIdx.x & 31, ty = threadIdx.x >> 5;  // 32 x 8
#pragma unroll
    for (int i = 0; i < 32; i += 8)
        tile[ty + i][tx] = in[(size_t)(by + ty + i) * DIM + bx + tx];
    __syncthreads();
#pragma unroll
    for (int i = 0; i < 32; i += 8)
        out[(size_t)(bx + ty + i) * DIM + by + tx] = tile[tx][ty + i];
}

// ------------------------------------------------- generic fp32 GEMM, 64x64 tile
// C[m][n] = sum_k A[m][k]*B[k][n] (+bias[n]) (+res[m][n]) (relu)
template<bool RELU, bool BIAS, bool RES>
__global__ __launch_bounds__(256) void gemm_ep(
    const float* __restrict__ A, const float* __restrict__ B,
    float* __restrict__ C, const float* __restrict__ bias,
    const float* __restrict__ res,
    int K, int lda, int ldb, int ldc,
    long long sA, long long sB, long long sC, int sBias)
{
    __shared__ float As[16][68];
    __shared__ float Bs[16][68];
    const int bx = blockIdx.x * 64, by = blockIdx.y * 64, bz = blockIdx.z;
    const int t = threadIdx.x, tx = t & 15, ty = t >> 4;
    const float* Ab = A + bz * sA + (long long)by * lda;
    const float* Bb = B + bz * sB + bx;
    float* Cb = C + bz * sC;

    const int lkk = t & 15, lm = t >> 4;     // A-load coords
    const int lnn = t & 63, lk2 = t >> 6;    // B-load coords

    float acc[4][4];
#pragma unroll
    for (int i = 0; i < 4; ++i)
#pragma unroll
        for (int j = 0; j < 4; ++j) acc[i][j] = 0.f;

    for (int k0 = 0; k0 < K; k0 += 16) {
#pragma unroll
        for (int p = 0; p < 4; ++p)
            As[lkk][lm + p * 16] = Ab[(long long)(lm + p * 16) * lda + k0 + lkk];
#pragma unroll
        for (int p = 0; p < 4; ++p)
            Bs[lk2 + p * 4][lnn] = Bb[(long long)(k0 + lk2 + p * 4) * ldb + lnn];
        __syncthreads();
#pragma unroll
        for (int kk = 0; kk < 16; ++kk) {
            float a_[4], b_[4];
            *(float4*)a_ = *(const float4*)&As[kk][ty * 4];
            *(float4*)b_ = *(const float4*)&Bs[kk][tx * 4];
#pragma unroll
            for (int i = 0; i < 4; ++i)
#pragma unroll
                for (int j = 0; j < 4; ++j)
                    acc[i][j] = fmaf(a_[i], b_[j], acc[i][j]);
        }
        __syncthreads();
    }

    const int crow0 = by + ty * 4, ccol = bx + tx * 4;
#pragma unroll
    for (int i = 0; i < 4; ++i) {
        float4 v = make_float4(acc[i][0], acc[i][1], acc[i][2], acc[i][3]);
        if (BIAS) {
            float4 b4 = *(const float4*)&bias[(long long)bz * sBias + ccol];
            v.x += b4.x; v.y += b4.y; v.z += b4.z; v.w += b4.w;
        }
        if (RES) {
            float4 r4 = *(const float4*)&res[(long long)(crow0 + i) * ldc + ccol];
            v.x += r4.x; v.y += r4.y; v.z += r4.z; v.w += r4.w;
        }
        if (RELU) {
            v.x = fmaxf(v.x, 0.f); v.y = fmaxf(v.y, 0.f);
            v.z = fmaxf(v.z, 0.f); v.w = fmaxf(v.w, 0.f);
        }
        *(float4*)&Cb[(long long)(crow0 + i) * ldc + ccol] = v;
    }
}

// ------------------------------------------------- K4: scores -> softmax -> a
// scores[n,h,k] = (k_in[k,:].u[n,h,:] + qh[n,h].bk_h)/8 ; a[n,h,:] = sum_k attn*v_in[k,:]
__global__ __launch_bounds__(256) void attn_mem_k(
    const float* qh, const float* u_in,
    const float* __restrict__ enc, const float* __restrict__ vemb,
    const int* __restrict__ maskmem, const int* __restrict__ samples,
    const float* __restrict__ bk, float* a_out /* aliases u_in, row-disjoint */)
{
    __shared__ float Us[NH * KPAD];
    __shared__ float Ks[16 * KPAD];
    __shared__ float Ss[NH][LM];
    __shared__ float Ps[16][NH][2];
    __shared__ float Cs[NH];
    const int n = blockIdx.x, t = threadIdx.x;
    int s = samples[n]; if (s < 0) s = 0;

    const float* un = u_in + (size_t)n * (NH * DIM);
#pragma unroll
    for (int i = t; i < NH * (DIM / 4); i += 256) {
        int h = i >> 7, c4 = i & 127;
        *(float4*)&Us[h * KPAD + c4 * 4] = ((const float4*)un)[i];
    }
    if (t < NH) {
        const float* q = qh + (size_t)n * DIM + t * DHD;
        float c = 0.f;
        for (int d = 0; d < DHD; ++d) c += q[d] * bk[t * DHD + d];
        Cs[t] = c;
    }
    __syncthreads();

    const float* kb = enc + (size_t)s * (LM * DIM);
    const int kk = t & 15, hh = (t >> 4) & 7, half = t >> 7;
    for (int kt = 0; kt < LM; kt += 16) {
#pragma unroll
        for (int i = t; i < 16 * (DIM / 4); i += 256) {
            int r = i >> 7, c4 = i & 127;
            *(float4*)&Ks[r * KPAD + c4 * 4] =
                *(const float4*)(kb + (size_t)(kt + r) * DIM + c4 * 4);
        }
        __syncthreads();
        const float* kr = &Ks[kk * KPAD + half * 256];
        const float* ur = &Us[hh * KPAD + half * 256];
        float p = 0.f;
#pragma unroll 8
        for (int d4 = 0; d4 < 64; ++d4) {
            float4 kv = *(const float4*)(kr + d4 * 4);
            float4 uv = *(const float4*)(ur + d4 * 4);
            p += kv.x * uv.x + kv.y * uv.y + kv.z * uv.z + kv.w * uv.w;
        }
        Ps[kk][hh][half] = p;
        __syncthreads();
        if (t < 128) Ss[t >> 4][kt + (t & 15)] = Ps[t & 15][t >> 4][0] + Ps[t & 15][t >> 4][1];
        __syncthreads();
    }

    const int* mrow = maskmem + (size_t)s * LM;
    for (int i = t; i < NH * LM; i += 256) {
        int h = i >> 6, k = i & 63;
        float sc = (Ss[h][k] + Cs[h]) * 0.125f;
        Ss[h][k] = (mrow[k] != 0) ? sc : -1e9f;
    }
    __syncthreads();
    if (t < NH) {
        float m = -INFINITY;
        for (int k = 0; k < LM; ++k) m = fmaxf(m, Ss[t][k]);
        float sum = 0.f;
        for (int k = 0; k < LM; ++k) { float e = expf(Ss[t][k] - m); Ss[t][k] = e; sum += e; }
        float inv = 1.f / sum;
        for (int k = 0; k < LM; ++k) Ss[t][k] *= inv;
    }
    __syncthreads();

    float acc[NH][2];
#pragma unroll
    for (int h = 0; h < NH; ++h) { acc[h][0] = 0.f; acc[h][1] = 0.f; }
    const float* vb = vemb + (size_t)s * (LM * DIM);
    const int d0 = t * 2;
    for (int kt = 0; kt < LM; kt += 16) {
#pragma unroll
        for (int i = t; i < 16 * (DIM / 4); i += 256) {
            int r = i >> 7, c4 = i & 127;
            *(float4*)&Ks[r * KPAD + c4 * 4] =
                *(const float4*)(vb + (size_t)(kt + r) * DIM + c4 * 4);
        }
        __syncthreads();
#pragma unroll
        for (int k = 0; k < 16; ++k) {
            float2 vv = *(const float2*)&Ks[k * KPAD + d0];
#pragma unroll
            for (int h = 0; h < NH; ++h) {
                float w = Ss[h][kt + k];
                acc[h][0] = fmaf(w, vv.x, acc[h][0]);
                acc[h][1] = fmaf(w, vv.y, acc[h][1]);
            }
        }
        __syncthreads();
    }
    float* an = a_out + (size_t)n * (NH * DIM);
#pragma unroll
    for (int h = 0; h < NH; ++h)
        *(float2*)&an[h * DIM + d0] = make_float2(acc[h][0], acc[h][1]);
}

// ------------------------------------------------- K8: LN(t1) mask + x residual
__global__ __launch_bounds__(256) void ln1_mask_add_k(
    const float* __restrict__ t1, const float* __restrict__ g,
    const float* __restrict__ be, const int* __restrict__ samples,
    const float* __restrict__ x, float* __restrict__ dec)
{
    __shared__ float red[4];
    const int n = blockIdx.x, t = threadIdx.x;
    float2 v = ((const float2*)(t1 + (size_t)n * DIM))[t];
    float mu  = blk_sum(v.x + v.y, red) * (1.f / DIM);
    float dx = v.x - mu, dy = v.y - mu;
    float var = blk_sum(dx * dx + dy * dy, red) * (1.f / DIM);
    float rs = rsqrtf(var + 1e-5f);
    float2 gg = ((const float2*)g)[t], bb = ((const float2*)be)[t];
    float sx = dx * rs * gg.x + bb.x, sy = dy * rs * gg.y + bb.y;
    if (samples[n] < 0) { sx = 0.f; sy = 0.f; }
    float2 xx = ((const float2*)(x + (size_t)n * DIM))[t];
    ((float2*)(dec + (size_t)n * DIM))[t] = make_float2(xx.x + sx, xx.y + sy);
}

// ---------------------------------------------------------------- launcher
extern "C" void kernel_launch(void* const* d_in, const int* in_sizes, int n_in,
                              void* d_out, int out_size, void* d_ws, size_t ws_size,
                              hipStream_t stream)
{
    const float* dec_output = (const float*)d_in[0];
    const float* mem_attn   = (const float*)d_in[1];
    const float* enc_mem    = (const float*)d_in[2];
    const float* temb_mem   = (const float*)d_in[3];
    const int*   mask_mem   = (const int*)d_in[4];
    // d_in[5] tgt_mask: unused by reference
    const float* g0  = (const float*)d_in[6];
    const float* be0 = (const float*)d_in[7];
    const float* g1  = (const float*)d_in[8];
    const float* be1 = (const float*)d_in[9];
    const float* Wq  = (const float*)d_in[10];
    const float* bq  = (const float*)d_in[11];
    const float* Wk  = (const float*)d_in[12];
    const float* bk  = (const float*)d_in[13];
    const float* Wv  = (const float*)d_in[14];
    const float* bv  = (const float*)d_in[15];
    const float* Wo  = (const float*)d_in[16];
    const float* bo  = (const float*)d_in[17];
    const float* f1W1 = (const float*)d_in[18];
    const float* f1b1 = (const float*)d_in[19];
    const float* f1W2 = (const float*)d_in[20];
    const float* f1b2 = (const float*)d_in[21];
    const float* f2W1 = (const float*)d_in[22];
    const float* f2b1 = (const float*)d_in[23];
    const float* f2W2 = (const float*)d_in[24];
    const float* f2b2 = (const float*)d_in[25];
    float* out = (float*)d_out;

    // workspace layout (floats)
    float* ws = (float*)d_ws;
    const size_t OFF_X   = 0;                       // 1024*512
    const size_t OFF_QH  = OFF_X   + (size_t)NQ * DIM;
    const size_t OFF_U   = OFF_QH  + (size_t)NQ * DIM;       // 1024*8*512 (aliased as 'a' after attn)
    const size_t OFF_WKT = OFF_U   + (size_t)NQ * NH * DIM;
    const size_t OFF_CTX = OFF_WKT + (size_t)DIM * DIM;
    const size_t OFF_ST0 = OFF_CTX + (size_t)NQ * DIM;
    const size_t OFF_H   = OFF_ST0 + (size_t)NQ * DIM;       // 1024*2048 (h1 then h2)
    const size_t OFF_T1  = OFF_H   + (size_t)NQ * DFF;
    const size_t OFF_DEC = OFF_T1  + (size_t)NQ * DIM;
    const size_t OFF_SMP = OFF_DEC + (size_t)NQ * DIM;
    float* x    = ws + OFF_X;
    float* qh   = ws + OFF_QH;
    float* u    = ws + OFF_U;      // also 'a'
    float* WkT  = ws + OFF_WKT;
    float* ctx  = ws + OFF_CTX;
    float* st0  = ws + OFF_ST0;
    float* hbuf = ws + OFF_H;
    float* t1   = ws + OFF_T1;
    float* dec  = ws + OFF_DEC;
    int*   smp  = (int*)(ws + OFF_SMP);

    // 1. LN0 + argmax
    ln0_argmax_k<<<NQ, 256, 0, stream>>>(dec_output, mem_attn, g0, be0, x, smp);
    // 2. WkT = Wk^T
    transpose512_k<<<dim3(16, 16), 256, 0, stream>>>(Wk, WkT);
    // 3. QH = X @ Wq + bq                       [1024,512]x[512,512]
    gemm_ep<false, true, false><<<dim3(8, 16, 1), 256, 0, stream>>>(
        x, Wq, qh, bq, nullptr, DIM, DIM, DIM, DIM, 0, 0, 0, 0);
    // 4. U_h = QH_h @ WkT_h  (batched over heads)  8x [1024,64]x[64,512]
    gemm_ep<false, false, false><<<dim3(8, 16, NH), 256, 0, stream>>>(
        qh, WkT, u, nullptr, nullptr, DHD, DIM, DIM, NH * DIM,
        /*sA*/ DHD, /*sB*/ (long long)DHD * DIM, /*sC*/ DIM, 0);
    // 5. scores -> softmax -> a  (a overwrites u, row-disjoint)
    attn_mem_k<<<NQ, 256, 0, stream>>>(qh, u, enc_mem, temb_mem, mask_mem, smp, bk, u);
    // 6. CTX_h = A_h @ Wv_h + bv_h (batched)       8x [1024,512]x[512,64]
    gemm_ep<false, true, false><<<dim3(1, 16, NH), 256, 0, stream>>>(
        u, Wv, ctx, bv, nullptr, DIM, NH * DIM, DIM, DIM,
        /*sA*/ DIM, /*sB*/ DHD, /*sC*/ DHD, /*sBias*/ DHD);
    // 7. ST0 = X + CTX @ Wo + bo
    gemm_ep<false, true, true><<<dim3(8, 16, 1), 256, 0, stream>>>(
        ctx, Wo, st0, bo, x, DIM, DIM, DIM, DIM, 0, 0, 0, 0);
    // 8. H1 = relu(ST0 @ f1W1 + f1b1)              [1024,512]x[512,2048]
    gemm_ep<true, true, false><<<dim3(32, 16, 1), 256, 0, stream>>>(
        st0, f1W1, hbuf, f1b1, nullptr, DIM, DIM, DFF, DFF, 0, 0, 0, 0);
    // 9. T1 = ST0 + H1 @ f1W2 + f1b2               [1024,2048]x[2048,512]
    gemm_ep<false, true, true><<<dim3(8, 16, 1), 256, 0, stream>>>(
        hbuf, f1W2, t1, f1b2, st0, DFF, DFF, DIM, DIM, 0, 0, 0, 0);
    // 10. DEC = X + mask * LN1(T1)
    ln1_mask_add_k<<<NQ, 256, 0, stream>>>(t1, g1, be1, smp, x, dec);
    // 11. H2 = relu(DEC @ f2W1 + f2b1)
    gemm_ep<true, true, false><<<dim3(32, 16, 1), 256, 0, stream>>>(
        dec, f2W1, hbuf, f2b1, nullptr, DIM, DIM, DFF, DFF, 0, 0, 0, 0);
    // 12. OUT = DEC + H2 @ f2W2 + f2b2  -> d_out
    gemm_ep<false, true, true><<<dim3(8, 16, 1), 256, 0, stream>>>(
        hbuf, f2W2, out, f2b2, dec, DFF, DFF, DIM, DIM, 0, 0, 0, 0);

    (void)in_sizes; (void)n_in; (void)out_size; (void)ws_size;
}

// Round 2
// 187.369 us; speedup vs baseline: 2.6789x; 2.6789x over previous
//
#include <hip/hip_runtime.h>
#include <math.h>

// Problem constants (fixed by the reference)
#define NQ   1024      // B*LT
#define DIM  512
#define NH   8
#define DHD  64
#define DFF  2048
#define LM   64        // LMEM
#define KPAD 516       // padded LDS row stride (floats)

typedef __bf16 bf16x8 __attribute__((ext_vector_type(8)));
typedef float  f32x4  __attribute__((ext_vector_type(4)));

__device__ __forceinline__ unsigned short f2bf(float f) {
    unsigned u = __builtin_bit_cast(unsigned, f);
    return (unsigned short)((u + 0x7fffu + ((u >> 16) & 1u)) >> 16);
}
__device__ __forceinline__ float bflo(unsigned p) {
    return __builtin_bit_cast(float, p << 16);
}
__device__ __forceinline__ float bfhi(unsigned p) {
    return __builtin_bit_cast(float, p & 0xffff0000u);
}

__device__ __forceinline__ void gload16(const void* g, void* l) {
    __builtin_amdgcn_global_load_lds(
        (const __attribute__((address_space(1))) unsigned*)g,
        (__attribute__((address_space(3))) unsigned*)l, 16, 0, 0);
}

// ---------------------------------------------------------------- helpers
__device__ __forceinline__ float blk_sum(float v, volatile float* red) {
#pragma unroll
    for (int o = 32; o; o >>= 1) v += __shfl_down(v, o);
    __syncthreads();
    if ((threadIdx.x & 63) == 0) red[threadIdx.x >> 6] = v;
    __syncthreads();
    return red[0] + red[1] + red[2] + red[3];
}

// ------------------------------------------------- K1: LN(dec_output) + argmax
__global__ __launch_bounds__(256) void ln0_argmax_k(
    const float* __restrict__ dec_out, const float* __restrict__ attn_out,
    const float* __restrict__ g, const float* __restrict__ be,
    float* __restrict__ x, unsigned* __restrict__ xb, int* __restrict__ samples)
{
    __shared__ float red[4];
    __shared__ float rv[4]; __shared__ int ri[4];
    const int n = blockIdx.x, t = threadIdx.x;

    float2 v = ((const float2*)(dec_out + (size_t)n * DIM))[t];
    float mu  = blk_sum(v.x + v.y, red) * (1.f / DIM);
    float dx = v.x - mu, dy = v.y - mu;
    float var = blk_sum(dx * dx + dy * dy, red) * (1.f / DIM);
    float rs = rsqrtf(var + 1e-5f);
    float2 gg = ((const float2*)g)[t], bb = ((const float2*)be)[t];
    float ox = dx * rs * gg.x + bb.x, oy = dy * rs * gg.y + bb.y;
    ((float2*)(x + (size_t)n * DIM))[t] = make_float2(ox, oy);
    xb[(size_t)n * 256 + t] = (unsigned)f2bf(ox) | ((unsigned)f2bf(oy) << 16);

    const float* ar = attn_out + (size_t)n * 1025;
    float bv = -INFINITY; int bi = 0x7fffffff;
    for (int i = t; i < 1025; i += 256) {
        float val = ar[i];
        if (val > bv || (val == bv && i < bi)) { bv = val; bi = i; }
    }
#pragma unroll
    for (int o = 32; o; o >>= 1) {
        float ov = __shfl_down(bv, o); int oi = __shfl_down(bi, o);
        if (ov > bv || (ov == bv && oi < bi)) { bv = ov; bi = oi; }
    }
    if ((t & 63) == 0) { rv[t >> 6] = bv; ri[t >> 6] = bi; }
    __syncthreads();
    if (t == 0) {
#pragma unroll
        for (int w = 1; w < 4; ++w)
            if (rv[w] > bv || (rv[w] == bv && ri[w] < bi)) { bv = rv[w]; bi = ri[w]; }
        samples[n] = bi - 1;
    }
}

// ------------------------------------------------- weight prep: fp32 -> bf16 (+T)
struct PrepPtrs {
    const float* src[8];
    unsigned short* dst[8];
};
// m: 0 WqT(T) 1 Wk(copy) 2 WvT(T) 3 WoT(T) 4 f1W1T(T,512x2048) 5 f1W2T(T,2048x512)
//    6 f2W1T(T,512x2048) 7 f2W2T(T,2048x512)
__global__ __launch_bounds__(256) void prep_weights_k(PrepPtrs p) {
    __shared__ float tile[32][33];
    const int bid = blockIdx.x;
    int m, lt;
    if (bid < 1024) { m = bid >> 8; lt = bid & 255; }
    else { m = 4 + ((bid - 1024) >> 10); lt = (bid - 1024) & 1023; }
    const int RS = (m < 4) ? 512 : ((m == 5 || m == 7) ? 2048 : 512);
    const int CS = (m < 4) ? 512 : ((m == 5 || m == 7) ? 512 : 2048);
    const int TC = CS >> 5;
    const int tr = lt / TC, tc = lt % TC;
    const float* s = p.src[m];
    unsigned short* d = p.dst[m];
    const int tx = threadIdx.x & 31, ty = threadIdx.x >> 5;
    if (m == 1) {
#pragma unroll
        for (int i = 0; i < 32; i += 8) {
            size_t idx = (size_t)(tr * 32 + ty + i) * CS + tc * 32 + tx;
            d[idx] = f2bf(s[idx]);
        }
    } else {
#pragma unroll
        for (int i = 0; i < 32; i += 8)
            tile[ty + i][tx] = s[(size_t)(tr * 32 + ty + i) * CS + tc * 32 + tx];
        __syncthreads();
#pragma unroll
        for (int i = 0; i < 32; i += 8)
            d[(size_t)(tc * 32 + ty + i) * RS + tr * 32 + tx] = f2bf(tile[tx][ty + i]);
    }
}

// ------------------------------------------------- bf16 MFMA GEMM, 64x64 tile
// C = A[M,K] @ Bt[N,K]^T (+bias) (+res) (relu); A,Bt bf16; C fp32 and/or bf16.
template<bool RELU, bool BIAS, bool RES, bool WF32, bool WBF>
__global__ __launch_bounds__(256) void mfma_gemm(
    const unsigned short* __restrict__ A, const unsigned short* __restrict__ Bt,
    float* __restrict__ Cf, unsigned short* __restrict__ Cb,
    const float* __restrict__ bias, const float* __restrict__ res,
    int K, int lda, int ldb, int ldc,
    int sA, int sB, int sC, int sBias)
{
    __shared__ unsigned short Ab[2][64 * 64];
    __shared__ unsigned short Bb[2][64 * 64];
    const int t = threadIdx.x, lane = t & 63, wid = t >> 6;
    const int bm = blockIdx.y * 64, bn = blockIdx.x * 64, bz = blockIdx.z;
    const unsigned short* Abase = A + (size_t)bz * sA + (size_t)bm * lda;
    const unsigned short* Bbase = Bt + (size_t)bz * sB + (size_t)bn * ldb;

    // staging geometry: wave w stages rows [w*16, w*16+16) in 2 issues of 8 rows
    const int r0 = wid * 16 + (lane >> 3);
    const int cbs = lane & 7;

#define STAGE_T(buf, base, ld, kt)                                              \
    {                                                                           \
        int r_ = r0;                                                            \
        gload16(base + (size_t)r_ * ld + (kt) * 64 + ((cbs ^ (r_ & 7)) << 3),   \
                &buf[(wid * 2 + 0) * 512]);                                     \
        r_ = r0 + 8;                                                            \
        gload16(base + (size_t)r_ * ld + (kt) * 64 + ((cbs ^ (r_ & 7)) << 3),   \
                &buf[(wid * 2 + 1) * 512]);                                     \
    }

    const int lr = lane & 15, lg = lane >> 4;
    const int wr = (wid >> 1) * 32, wc = (wid & 1) * 32;
    const int mA0 = wr + lr, mA1 = wr + 16 + lr;
    const int nB0 = wc + lr, nB1 = wc + 16 + lr;
    f32x4 acc[2][2] = {};

#define COMPUTE(b)                                                              \
    _Pragma("unroll")                                                           \
    for (int kk = 0; kk < 2; ++kk) {                                            \
        const int kb = kk * 4 + lg;                                             \
        bf16x8 a0 = *(const bf16x8*)&Ab[b][mA0 * 64 + ((kb ^ (mA0 & 7)) << 3)]; \
        bf16x8 a1 = *(const bf16x8*)&Ab[b][mA1 * 64 + ((kb ^ (mA1 & 7)) << 3)]; \
        bf16x8 b0 = *(const bf16x8*)&Bb[b][nB0 * 64 + ((kb ^ (nB0 & 7)) << 3)]; \
        bf16x8 b1 = *(const bf16x8*)&Bb[b][nB1 * 64 + ((kb ^ (nB1 & 7)) << 3)]; \
        acc[0][0] = __builtin_amdgcn_mfma_f32_16x16x32_bf16(a0, b0, acc[0][0], 0, 0, 0); \
        acc[0][1] = __builtin_amdgcn_mfma_f32_16x16x32_bf16(a0, b1, acc[0][1], 0, 0, 0); \
        acc[1][0] = __builtin_amdgcn_mfma_f32_16x16x32_bf16(a1, b0, acc[1][0], 0, 0, 0); \
        acc[1][1] = __builtin_amdgcn_mfma_f32_16x16x32_bf16(a1, b1, acc[1][1], 0, 0, 0); \
    }

    STAGE_T(Ab[0], Abase, lda, 0);
    STAGE_T(Bb[0], Bbase, ldb, 0);
    __syncthreads();
    const int NT = K >> 6;
    int cur = 0;
    for (int kt = 0; kt < NT; ++kt) {
        if (kt + 1 < NT) {
            STAGE_T(Ab[cur ^ 1], Abase, lda, kt + 1);
            STAGE_T(Bb[cur ^ 1], Bbase, ldb, kt + 1);
        }
        if (cur == 0) { COMPUTE(0); } else { COMPUTE(1); }
        __syncthreads();
        cur ^= 1;
    }

#pragma unroll
    for (int fm = 0; fm < 2; ++fm)
#pragma unroll
    for (int fn = 0; fn < 2; ++fn) {
        const int col = bn + wc + fn * 16 + lr;
        float bia = BIAS ? bias[bz * sBias + col] : 0.f;
#pragma unroll
        for (int r = 0; r < 4; ++r) {
            const int row = bm + wr + fm * 16 + lg * 4 + r;
            const size_t ci = (size_t)bz * sC + (size_t)row * ldc + col;
            float v = acc[fm][fn][r] + bia;
            if (RES) v += res[(size_t)row * ldc + col];
            if (RELU) v = fmaxf(v, 0.f);
            if (WF32) Cf[ci] = v;
            if (WBF)  Cb[ci] = f2bf(v);
        }
    }
#undef STAGE_T
#undef COMPUTE
}

// ------------------------------------------------- K5: scores -> softmax -> a
__global__ __launch_bounds__(256) void attn_mem_k(
    const float* __restrict__ qh, const unsigned short* __restrict__ u_bf,
    const float* __restrict__ enc, const float* __restrict__ vemb,
    const int* __restrict__ maskmem, const int* __restrict__ samples,
    const float* __restrict__ bk, unsigned* __restrict__ a_bf)
{
    __shared__ float Us[NH * KPAD];
    __shared__ float Ks[16 * KPAD];
    __shared__ float Ss[NH][LM];
    __shared__ float Ps[16][NH][2];
    __shared__ float Cs[NH];
    const int n = blockIdx.x, t = threadIdx.x;
    int s = samples[n]; if (s < 0) s = 0;

    const unsigned* un = (const unsigned*)u_bf + (size_t)n * 2048;
    for (int i = t; i < 2048; i += 256) {
        unsigned p = un[i];
        int e = i * 2;
        int h = e >> 9, c = e & 511;
        Us[h * KPAD + c]     = bflo(p);
        Us[h * KPAD + c + 1] = bfhi(p);
    }
    if (t < NH) {
        const float* q = qh + (size_t)n * DIM + t * DHD;
        float c = 0.f;
        for (int d = 0; d < DHD; ++d) c += q[d] * bk[t * DHD + d];
        Cs[t] = c;
    }
    __syncthreads();

    const float* kb = enc + (size_t)s * (LM * DIM);
    const int kk = t & 15, hh = (t >> 4) & 7, half = t >> 7;
    for (int kt = 0; kt < LM; kt += 16) {
        for (int i = t; i < 16 * (DIM / 4); i += 256) {
            int r = i >> 7, c4 = i & 127;
            *(float4*)&Ks[r * KPAD + c4 * 4] =
                *(const float4*)(kb + (size_t)(kt + r) * DIM + c4 * 4);
        }
        __syncthreads();
        const float* kr = &Ks[kk * KPAD + half * 256];
        const float* ur = &Us[hh * KPAD + half * 256];
        float p = 0.f;
#pragma unroll 8
        for (int d4 = 0; d4 < 64; ++d4) {
            float4 kv = *(const float4*)(kr + d4 * 4);
            float4 uv = *(const float4*)(ur + d4 * 4);
            p += kv.x * uv.x + kv.y * uv.y + kv.z * uv.z + kv.w * uv.w;
        }
        Ps[kk][hh][half] = p;
        __syncthreads();
        if (t < 128) Ss[t >> 4][kt + (t & 15)] = Ps[t & 15][t >> 4][0] + Ps[t & 15][t >> 4][1];
        __syncthreads();
    }

    const int* mrow = maskmem + (size_t)s * LM;
    for (int i = t; i < NH * LM; i += 256) {
        int h = i >> 6, k = i & 63;
        float sc = (Ss[h][k] + Cs[h]) * 0.125f;
        Ss[h][k] = (mrow[k] != 0) ? sc : -1e9f;
    }
    __syncthreads();
    if (t < NH) {
        float m = -INFINITY;
        for (int k = 0; k < LM; ++k) m = fmaxf(m, Ss[t][k]);
        float sum = 0.f;
        for (int k = 0; k < LM; ++k) { float e = expf(Ss[t][k] - m); Ss[t][k] = e; sum += e; }
        float inv = 1.f / sum;
        for (int k = 0; k < LM; ++k) Ss[t][k] *= inv;
    }
    __syncthreads();

    float acc[NH][2];
#pragma unroll
    for (int h = 0; h < NH; ++h) { acc[h][0] = 0.f; acc[h][1] = 0.f; }
    const float* vb = vemb + (size_t)s * (LM * DIM);
    const int d0 = t * 2;
    for (int kt = 0; kt < LM; kt += 16) {
        for (int i = t; i < 16 * (DIM / 4); i += 256) {
            int r = i >> 7, c4 = i & 127;
            *(float4*)&Ks[r * KPAD + c4 * 4] =
                *(const float4*)(vb + (size_t)(kt + r) * DIM + c4 * 4);
        }
        __syncthreads();
#pragma unroll
        for (int k = 0; k < 16; ++k) {
            float2 vv = *(const float2*)&Ks[k * KPAD + d0];
#pragma unroll
            for (int h = 0; h < NH; ++h) {
                float w = Ss[h][kt + k];
                acc[h][0] = fmaf(w, vv.x, acc[h][0]);
                acc[h][1] = fmaf(w, vv.y, acc[h][1]);
            }
        }
        __syncthreads();
    }
    unsigned* an = a_bf + (size_t)n * 2048;
#pragma unroll
    for (int h = 0; h < NH; ++h)
        an[h * 256 + t] = (unsigned)f2bf(acc[h][0]) | ((unsigned)f2bf(acc[h][1]) << 16);
}

// ------------------------------------------------- K10: LN(t1) mask + x residual
__global__ __launch_bounds__(256) void ln1_mask_add_k(
    const float* __restrict__ t1, const float* __restrict__ g,
    const float* __restrict__ be, const int* __restrict__ samples,
    const float* __restrict__ x, float* __restrict__ dec, unsigned* __restrict__ decb)
{
    __shared__ float red[4];
    const int n = blockIdx.x, t = threadIdx.x;
    float2 v = ((const float2*)(t1 + (size_t)n * DIM))[t];
    float mu  = blk_sum(v.x + v.y, red) * (1.f / DIM);
    float dx = v.x - mu, dy = v.y - mu;
    float var = blk_sum(dx * dx + dy * dy, red) * (1.f / DIM);
    float rs = rsqrtf(var + 1e-5f);
    float2 gg = ((const float2*)g)[t], bb = ((const float2*)be)[t];
    float sx = dx * rs * gg.x + bb.x, sy = dy * rs * gg.y + bb.y;
    if (samples[n] < 0) { sx = 0.f; sy = 0.f; }
    float2 xx = ((const float2*)(x + (size_t)n * DIM))[t];
    float ox = xx.x + sx, oy = xx.y + sy;
    ((float2*)(dec + (size_t)n * DIM))[t] = make_float2(ox, oy);
    decb[(size_t)n * 256 + t] = (unsigned)f2bf(ox) | ((unsigned)f2bf(oy) << 16);
}

// ---------------------------------------------------------------- launcher
extern "C" void kernel_launch(void* const* d_in, const int* in_sizes, int n_in,
                              void* d_out, int out_size, void* d_ws, size_t ws_size,
                              hipStream_t stream)
{
    const float* dec_output = (const float*)d_in[0];
    const float* mem_attn   = (const float*)d_in[1];
    const float* enc_mem    = (const float*)d_in[2];
    const float* temb_mem   = (const float*)d_in[3];
    const int*   mask_mem   = (const int*)d_in[4];
    const float* g0  = (const float*)d_in[6];
    const float* be0 = (const float*)d_in[7];
    const float* g1  = (const float*)d_in[8];
    const float* be1 = (const float*)d_in[9];
    const float* Wq  = (const float*)d_in[10];
    const float* bq  = (const float*)d_in[11];
    const float* Wk  = (const float*)d_in[12];
    const float* bk  = (const float*)d_in[13];
    const float* Wv  = (const float*)d_in[14];
    const float* bv  = (const float*)d_in[15];
    const float* Wo  = (const float*)d_in[16];
    const float* bo  = (const float*)d_in[17];
    const float* f1W1 = (const float*)d_in[18];
    const float* f1b1 = (const float*)d_in[19];
    const float* f1W2 = (const float*)d_in[20];
    const float* f1b2 = (const float*)d_in[21];
    const float* f2W1 = (const float*)d_in[22];
    const float* f2b1 = (const float*)d_in[23];
    const float* f2W2 = (const float*)d_in[24];
    const float* f2b2 = (const float*)d_in[25];
    float* out = (float*)d_out;

    float* ws = (float*)d_ws;
    // persistent buffers (offsets in floats)
    float*          x_f   = ws + 0;                    // 524288
    unsigned*       x_b   = (unsigned*)(ws + 524288);  // 262144 f
    float*          qh_f  = ws + 786432;               // 524288
    unsigned short* qh_b  = (unsigned short*)(ws + 1310720); // 262144 f
    unsigned short* u_b   = (unsigned short*)(ws + 1572864); // 2097152 f (1024x4096 bf16)
    unsigned short* a_b   = (unsigned short*)(ws + 3670016); // 2097152 f
    unsigned short* wqt   = (unsigned short*)(ws + 5767168); // 131072 f each
    unsigned short* wkc   = (unsigned short*)(ws + 5898240);
    unsigned short* wvt   = (unsigned short*)(ws + 6029312);
    unsigned short* wot   = (unsigned short*)(ws + 6160384);
    unsigned short* f1w1t = (unsigned short*)(ws + 6291456); // 524288 f each
    unsigned short* f1w2t = (unsigned short*)(ws + 6815744);
    unsigned short* f2w1t = (unsigned short*)(ws + 7340032);
    unsigned short* f2w2t = (unsigned short*)(ws + 7864320);
    int*            smp   = (int*)(ws + 8388608);
    // aliased (inside u_b region, dead after attn):
    float*          st0_f = (float*)u_b + 0;
    unsigned short* st0_b = (unsigned short*)((float*)u_b + 524288);
    float*          t1_f  = (float*)u_b + 786432;
    float*          dec_f = (float*)u_b + 1310720;
    unsigned*       dec_b = (unsigned*)((float*)u_b + 1835008);
    // aliased (inside a_b region, dead after G6):
    unsigned short* h1_b  = a_b;
    unsigned short* h2_b  = (unsigned short*)((float*)a_b + 1048576);

    // 1. weight prep (bf16 + transpose)
    PrepPtrs pp;
    pp.src[0] = Wq;   pp.dst[0] = wqt;
    pp.src[1] = Wk;   pp.dst[1] = wkc;
    pp.src[2] = Wv;   pp.dst[2] = wvt;
    pp.src[3] = Wo;   pp.dst[3] = wot;
    pp.src[4] = f1W1; pp.dst[4] = f1w1t;
    pp.src[5] = f1W2; pp.dst[5] = f1w2t;
    pp.src[6] = f2W1; pp.dst[6] = f2w1t;
    pp.src[7] = f2W2; pp.dst[7] = f2w2t;
    prep_weights_k<<<5120, 256, 0, stream>>>(pp);
    // 2. LN0 + argmax
    ln0_argmax_k<<<NQ, 256, 0, stream>>>(dec_output, mem_attn, g0, be0, x_f, x_b, smp);
    // 3. QH = X @ Wq + bq  -> f32 + bf16
    mfma_gemm<false, true, false, true, true><<<dim3(8, 16, 1), 256, 0, stream>>>(
        (const unsigned short*)x_b, wqt, qh_f, qh_b, bq, nullptr,
        DIM, DIM, DIM, DIM, 0, 0, 0, 0);
    // 4. U_h = QH_h @ Wk_h^T  (batched, K=64) -> bf16
    mfma_gemm<false, false, false, false, true><<<dim3(8, 16, NH), 256, 0, stream>>>(
        qh_b, wkc, nullptr, u_b, nullptr, nullptr,
        DHD, DIM, DIM, NH * DIM, /*sA*/ DHD, /*sB*/ DHD, /*sC*/ DIM, 0);
    // 5. scores -> softmax -> a (bf16)
    attn_mem_k<<<NQ, 256, 0, stream>>>(qh_f, u_b, enc_mem, temb_mem, mask_mem, smp,
                                       bk, (unsigned*)a_b);
    // 6. CTX_h = A_h @ Wv_h + bv_h (batched) -> bf16 (into qh_b, dead)
    mfma_gemm<false, true, false, false, true><<<dim3(1, 16, NH), 256, 0, stream>>>(
        a_b, wvt, nullptr, qh_b, bv, nullptr,
        DIM, NH * DIM, DIM, DIM, /*sA*/ DIM, /*sB*/ DHD * DIM, /*sC*/ DHD, /*sBias*/ DHD);
    // 7. ST0 = X + CTX @ Wo + bo -> f32 + bf16
    mfma_gemm<false, true, true, true, true><<<dim3(8, 16, 1), 256, 0, stream>>>(
        qh_b, wot, st0_f, st0_b, bo, x_f, DIM, DIM, DIM, DIM, 0, 0, 0, 0);
    // 8. H1 = relu(ST0 @ f1W1 + f1b1) -> bf16
    mfma_gemm<true, true, false, false, true><<<dim3(32, 16, 1), 256, 0, stream>>>(
        st0_b, f1w1t, nullptr, h1_b, f1b1, nullptr, DIM, DIM, DIM, DFF, 0, 0, 0, 0);
    // 9. T1 = ST0 + H1 @ f1W2 + f1b2 -> f32
    mfma_gemm<false, true, true, true, false><<<dim3(8, 16, 1), 256, 0, stream>>>(
        h1_b, f1w2t, t1_f, nullptr, f1b2, st0_f, DFF, DFF, DFF, DIM, 0, 0, 0, 0);
    // 10. DEC = X + mask * LN1(T1) -> f32 + bf16
    ln1_mask_add_k<<<NQ, 256, 0, stream>>>(t1_f, g1, be1, smp, x_f, dec_f, dec_b);
    // 11. H2 = relu(DEC @ f2W1 + f2b1) -> bf16
    mfma_gemm<true, true, false, false, true><<<dim3(32, 16, 1), 256, 0, stream>>>(
        (const unsigned short*)dec_b, f2w1t, nullptr, h2_b, f2b1, nullptr,
        DIM, DIM, DIM, DFF, 0, 0, 0, 0);
    // 12. OUT = DEC + H2 @ f2W2 + f2b2 -> d_out (f32)
    mfma_gemm<false, true, true, true, false><<<dim3(8, 16, 1), 256, 0, stream>>>(
        h2_b, f2w2t, out, nullptr, f2b2, dec_f, DFF, DFF, DFF, DIM, 0, 0, 0, 0);

    (void)in_sizes; (void)n_in; (void)out_size; (void)ws_size;
}

// Round 3
// 162.670 us; speedup vs baseline: 3.0856x; 1.1518x over previous
//
#include <hip/hip_runtime.h>
#include <math.h>

// Problem constants (fixed by the reference)
#define NQ   1024      // B*LT
#define DIM  512
#define NH   8
#define DHD  64
#define DFF  2048
#define LM   64        // LMEM

typedef __bf16 bf16x8 __attribute__((ext_vector_type(8)));
typedef float  f32x4  __attribute__((ext_vector_type(4)));

__device__ __forceinline__ unsigned short f2bf(float f) {
    unsigned u = __builtin_bit_cast(unsigned, f);
    return (unsigned short)((u + 0x7fffu + ((u >> 16) & 1u)) >> 16);
}
__device__ __forceinline__ float bflo(unsigned p) {
    return __builtin_bit_cast(float, p << 16);
}
__device__ __forceinline__ float bfhi(unsigned p) {
    return __builtin_bit_cast(float, p & 0xffff0000u);
}

__device__ __forceinline__ void gload16(const void* g, void* l) {
    __builtin_amdgcn_global_load_lds(
        (const __attribute__((address_space(1))) unsigned*)g,
        (__attribute__((address_space(3))) unsigned*)l, 16, 0, 0);
}

// ---------------------------------------------------------------- helpers
__device__ __forceinline__ float blk_sum(float v, volatile float* red) {
#pragma unroll
    for (int o = 32; o; o >>= 1) v += __shfl_down(v, o);
    __syncthreads();
    if ((threadIdx.x & 63) == 0) red[threadIdx.x >> 6] = v;
    __syncthreads();
    return red[0] + red[1] + red[2] + red[3];
}

// ------------------------------------------------- K1: LN(dec_output) + argmax
__global__ __launch_bounds__(256) void ln0_argmax_k(
    const float* __restrict__ dec_out, const float* __restrict__ attn_out,
    const float* __restrict__ g, const float* __restrict__ be,
    float* __restrict__ x, unsigned* __restrict__ xb, int* __restrict__ samples)
{
    __shared__ float red[4];
    __shared__ float rv[4]; __shared__ int ri[4];
    const int n = blockIdx.x, t = threadIdx.x;

    float2 v = ((const float2*)(dec_out + (size_t)n * DIM))[t];
    float mu  = blk_sum(v.x + v.y, red) * (1.f / DIM);
    float dx = v.x - mu, dy = v.y - mu;
    float var = blk_sum(dx * dx + dy * dy, red) * (1.f / DIM);
    float rs = rsqrtf(var + 1e-5f);
    float2 gg = ((const float2*)g)[t], bb = ((const float2*)be)[t];
    float ox = dx * rs * gg.x + bb.x, oy = dy * rs * gg.y + bb.y;
    ((float2*)(x + (size_t)n * DIM))[t] = make_float2(ox, oy);
    xb[(size_t)n * 256 + t] = (unsigned)f2bf(ox) | ((unsigned)f2bf(oy) << 16);

    const float* ar = attn_out + (size_t)n * 1025;
    float bv = -INFINITY; int bi = 0x7fffffff;
    for (int i = t; i < 1025; i += 256) {
        float val = ar[i];
        if (val > bv || (val == bv && i < bi)) { bv = val; bi = i; }
    }
#pragma unroll
    for (int o = 32; o; o >>= 1) {
        float ov = __shfl_down(bv, o); int oi = __shfl_down(bi, o);
        if (ov > bv || (ov == bv && oi < bi)) { bv = ov; bi = oi; }
    }
    if ((t & 63) == 0) { rv[t >> 6] = bv; ri[t >> 6] = bi; }
    __syncthreads();
    if (t == 0) {
#pragma unroll
        for (int w = 1; w < 4; ++w)
            if (rv[w] > bv || (rv[w] == bv && ri[w] < bi)) { bv = rv[w]; bi = ri[w]; }
        samples[n] = bi - 1;
    }
}

// ------------------------------------------------- weight prep: fp32 -> bf16 (+T)
struct PrepPtrs {
    const float* src[8];
    unsigned short* dst[8];
};
__global__ __launch_bounds__(256) void prep_weights_k(PrepPtrs p) {
    __shared__ float tile[32][33];
    const int bid = blockIdx.x;
    int m, lt;
    if (bid < 1024) { m = bid >> 8; lt = bid & 255; }
    else { m = 4 + ((bid - 1024) >> 10); lt = (bid - 1024) & 1023; }
    const int RS = (m < 4) ? 512 : ((m == 5 || m == 7) ? 2048 : 512);
    const int CS = (m < 4) ? 512 : ((m == 5 || m == 7) ? 512 : 2048);
    const int TC = CS >> 5;
    const int tr = lt / TC, tc = lt % TC;
    const float* s = p.src[m];
    unsigned short* d = p.dst[m];
    const int tx = threadIdx.x & 31, ty = threadIdx.x >> 5;
    if (m == 1) {
#pragma unroll
        for (int i = 0; i < 32; i += 8) {
            size_t idx = (size_t)(tr * 32 + ty + i) * CS + tc * 32 + tx;
            d[idx] = f2bf(s[idx]);
        }
    } else {
#pragma unroll
        for (int i = 0; i < 32; i += 8)
            tile[ty + i][tx] = s[(size_t)(tr * 32 + ty + i) * CS + tc * 32 + tx];
        __syncthreads();
#pragma unroll
        for (int i = 0; i < 32; i += 8)
            d[(size_t)(tc * 32 + ty + i) * RS + tr * 32 + tx] = f2bf(tile[tx][ty + i]);
    }
}

// ------------------------------------------------- bf16 MFMA GEMM, 64x64 tile
template<bool RELU, bool BIAS, bool RES, bool WF32, bool WBF>
__global__ __launch_bounds__(256) void mfma_gemm(
    const unsigned short* __restrict__ A, const unsigned short* __restrict__ Bt,
    float* __restrict__ Cf, unsigned short* __restrict__ Cb,
    const float* __restrict__ bias, const float* __restrict__ res,
    int K, int lda, int ldb, int ldc,
    int sA, int sB, int sC, int sBias)
{
    __shared__ unsigned short Ab[2][64 * 64];
    __shared__ unsigned short Bb[2][64 * 64];
    const int t = threadIdx.x, lane = t & 63, wid = t >> 6;
    const int bm = blockIdx.y * 64, bn = blockIdx.x * 64, bz = blockIdx.z;
    const unsigned short* Abase = A + (size_t)bz * sA + (size_t)bm * lda;
    const unsigned short* Bbase = Bt + (size_t)bz * sB + (size_t)bn * ldb;

    const int r0 = wid * 16 + (lane >> 3);
    const int cbs = lane & 7;

#define STAGE_T(buf, base, ld, kt)                                              \
    {                                                                           \
        int r_ = r0;                                                            \
        gload16(base + (size_t)r_ * ld + (kt) * 64 + ((cbs ^ (r_ & 7)) << 3),   \
                &buf[(wid * 2 + 0) * 512]);                                     \
        r_ = r0 + 8;                                                            \
        gload16(base + (size_t)r_ * ld + (kt) * 64 + ((cbs ^ (r_ & 7)) << 3),   \
                &buf[(wid * 2 + 1) * 512]);                                     \
    }

    const int lr = lane & 15, lg = lane >> 4;
    const int wr = (wid >> 1) * 32, wc = (wid & 1) * 32;
    const int mA0 = wr + lr, mA1 = wr + 16 + lr;
    const int nB0 = wc + lr, nB1 = wc + 16 + lr;
    f32x4 acc[2][2] = {};

#define COMPUTE(b)                                                              \
    _Pragma("unroll")                                                           \
    for (int kk = 0; kk < 2; ++kk) {                                            \
        const int kb = kk * 4 + lg;                                             \
        bf16x8 a0 = *(const bf16x8*)&Ab[b][mA0 * 64 + ((kb ^ (mA0 & 7)) << 3)]; \
        bf16x8 a1 = *(const bf16x8*)&Ab[b][mA1 * 64 + ((kb ^ (mA1 & 7)) << 3)]; \
        bf16x8 b0 = *(const bf16x8*)&Bb[b][nB0 * 64 + ((kb ^ (nB0 & 7)) << 3)]; \
        bf16x8 b1 = *(const bf16x8*)&Bb[b][nB1 * 64 + ((kb ^ (nB1 & 7)) << 3)]; \
        acc[0][0] = __builtin_amdgcn_mfma_f32_16x16x32_bf16(a0, b0, acc[0][0], 0, 0, 0); \
        acc[0][1] = __builtin_amdgcn_mfma_f32_16x16x32_bf16(a0, b1, acc[0][1], 0, 0, 0); \
        acc[1][0] = __builtin_amdgcn_mfma_f32_16x16x32_bf16(a1, b0, acc[1][0], 0, 0, 0); \
        acc[1][1] = __builtin_amdgcn_mfma_f32_16x16x32_bf16(a1, b1, acc[1][1], 0, 0, 0); \
    }

    STAGE_T(Ab[0], Abase, lda, 0);
    STAGE_T(Bb[0], Bbase, ldb, 0);
    __syncthreads();
    const int NT = K >> 6;
    int cur = 0;
    for (int kt = 0; kt < NT; ++kt) {
        if (kt + 1 < NT) {
            STAGE_T(Ab[cur ^ 1], Abase, lda, kt + 1);
            STAGE_T(Bb[cur ^ 1], Bbase, ldb, kt + 1);
        }
        if (cur == 0) { COMPUTE(0); } else { COMPUTE(1); }
        __syncthreads();
        cur ^= 1;
    }

#pragma unroll
    for (int fm = 0; fm < 2; ++fm)
#pragma unroll
    for (int fn = 0; fn < 2; ++fn) {
        const int col = bn + wc + fn * 16 + lr;
        float bia = BIAS ? bias[bz * sBias + col] : 0.f;
#pragma unroll
        for (int r = 0; r < 4; ++r) {
            const int row = bm + wr + fm * 16 + lg * 4 + r;
            const size_t ci = (size_t)bz * sC + (size_t)row * ldc + col;
            float v = acc[fm][fn][r] + bia;
            if (RES) v += res[(size_t)row * ldc + col];
            if (RELU) v = fmaxf(v, 0.f);
            if (WF32) Cf[ci] = v;
            if (WBF)  Cb[ci] = f2bf(v);
        }
    }
#undef STAGE_T
#undef COMPUTE
}

// ------------------------------------------------- K5: scores(MFMA) -> softmax -> PV
// scores[k,h] = enc[s,k,:]·u[n,h,:] (+ qh·bk_h), A-frag direct from global.
__global__ __launch_bounds__(256) void attn_mem_k(
    const float* __restrict__ qh, const unsigned short* __restrict__ u_bf,
    const float* __restrict__ enc, const float* __restrict__ vemb,
    const int* __restrict__ maskmem, const int* __restrict__ samples,
    const float* __restrict__ bk, unsigned* __restrict__ a_bf)
{
    __shared__ alignas(16) unsigned short U_lds[16 * 512]; // bf16, swizzled
    __shared__ float S_lds[8 * 68];
    __shared__ alignas(16) unsigned short P_lds[64 * 8];   // bf16 [k][h]
    __shared__ float Cs_lds[8];
    __shared__ int Msk_lds[64];

    const int n = blockIdx.x, t = threadIdx.x;
    const int lane = t & 63, w = t >> 6;
    int s = samples[n]; if (s < 0) s = 0;

    // ---- phase 1: stage U (rows 0-7 data, 8-15 zeros), mask, Cs = qh·bk
    {
        const uint4* ub = (const uint4*)(u_bf + (size_t)n * 4096);
#pragma unroll
        for (int i = 0; i < 4; ++i) {
            int chunk = t + i * 256;          // [0,1024)
            int h = chunk >> 6, c8 = chunk & 63;
            uint4 v = (h < 8) ? ub[chunk] : make_uint4(0, 0, 0, 0);
            *(uint4*)&U_lds[h * 512 + (c8 ^ (h & 7)) * 8] = v;
        }
        if (w == 0) Msk_lds[lane] = maskmem[(size_t)s * LM + lane];
        if (w == 1) {
            int h = lane >> 3, j = lane & 7;
            const float4* q4 = (const float4*)(qh + (size_t)n * DIM + h * 64 + j * 8);
            const float4* b4 = (const float4*)(bk + h * 64 + j * 8);
            float4 qa = q4[0], qb = q4[1], ba = b4[0], bb = b4[1];
            float c = qa.x * ba.x + qa.y * ba.y + qa.z * ba.z + qa.w * ba.w
                    + qb.x * bb.x + qb.y * bb.y + qb.z * bb.z + qb.w * bb.w;
            c += __shfl_xor(c, 1); c += __shfl_xor(c, 2); c += __shfl_xor(c, 4);
            if (j == 0) Cs_lds[h] = c;
        }
    }
    __syncthreads();

    // ---- phase 2: scores via MFMA (wave w: keys [w*16, w*16+16), 16 head-cols)
    {
        const float4* kb = (const float4*)(enc + (size_t)s * (LM * DIM));
        const int key = w * 16 + (lane & 15);
        const int lg = lane >> 4;
        const int h = lane & 15;
        const int base = key * 128 + lg * 2;  // float4 index, step 0
        f32x4 acc = {};
        float4 pf[4][2];
#pragma unroll
        for (int ss = 0; ss < 4; ++ss) {
            pf[ss][0] = kb[base + ss * 8];
            pf[ss][1] = kb[base + ss * 8 + 1];
        }
#pragma unroll
        for (int step = 0; step < 16; ++step) {
            float4 a0 = pf[step & 3][0], a1 = pf[step & 3][1];
            if (step + 4 < 16) {
                pf[step & 3][0] = kb[base + (step + 4) * 8];
                pf[step & 3][1] = kb[base + (step + 4) * 8 + 1];
            }
            bf16x8 af;
            af[0] = (__bf16)a0.x; af[1] = (__bf16)a0.y;
            af[2] = (__bf16)a0.z; af[3] = (__bf16)a0.w;
            af[4] = (__bf16)a1.x; af[5] = (__bf16)a1.y;
            af[6] = (__bf16)a1.z; af[7] = (__bf16)a1.w;
            const int c8 = step * 4 + lg;
            bf16x8 bfr = *(const bf16x8*)&U_lds[h * 512 + (c8 ^ (h & 7)) * 8];
            acc = __builtin_amdgcn_mfma_f32_16x16x32_bf16(af, bfr, acc, 0, 0, 0);
        }
        if (h < 8) {
#pragma unroll
            for (int r = 0; r < 4; ++r)
                S_lds[h * 68 + w * 16 + lg * 4 + r] = acc[r];
        }
    }
    __syncthreads();

    // ---- phase 3: wave-parallel softmax (wave w: heads w and w+4)
#pragma unroll
    for (int hh = 0; hh < 2; ++hh) {
        const int h = w + hh * 4;
        float sc = (S_lds[h * 68 + lane] + Cs_lds[h]) * 0.125f;
        sc = (Msk_lds[lane] != 0) ? sc : -1e9f;
        float m = sc;
#pragma unroll
        for (int o = 32; o; o >>= 1) m = fmaxf(m, __shfl_xor(m, o));
        float e = __expf(sc - m);
        float su = e;
#pragma unroll
        for (int o = 32; o; o >>= 1) su += __shfl_xor(su, o);
        P_lds[lane * 8 + h] = f2bf(e / su);
    }
    __syncthreads();

    // ---- phase 4: PV outer-product, V direct from global (d0 = 2t)
    {
        float2 acc8[8];
#pragma unroll
        for (int h = 0; h < 8; ++h) acc8[h] = make_float2(0.f, 0.f);
        const float2* vb = (const float2*)(vemb + (size_t)s * (LM * DIM)) + t;
#pragma unroll 8
        for (int k = 0; k < 64; ++k) {
            float2 v = vb[k * 256];
            uint4 pr = *(const uint4*)&P_lds[k * 8];
            float p0 = bflo(pr.x), p1 = bfhi(pr.x);
            float p2 = bflo(pr.y), p3 = bfhi(pr.y);
            float p4 = bflo(pr.z), p5 = bfhi(pr.z);
            float p6 = bflo(pr.w), p7 = bfhi(pr.w);
            acc8[0].x = fmaf(p0, v.x, acc8[0].x); acc8[0].y = fmaf(p0, v.y, acc8[0].y);
            acc8[1].x = fmaf(p1, v.x, acc8[1].x); acc8[1].y = fmaf(p1, v.y, acc8[1].y);
            acc8[2].x = fmaf(p2, v.x, acc8[2].x); acc8[2].y = fmaf(p2, v.y, acc8[2].y);
            acc8[3].x = fmaf(p3, v.x, acc8[3].x); acc8[3].y = fmaf(p3, v.y, acc8[3].y);
            acc8[4].x = fmaf(p4, v.x, acc8[4].x); acc8[4].y = fmaf(p4, v.y, acc8[4].y);
            acc8[5].x = fmaf(p5, v.x, acc8[5].x); acc8[5].y = fmaf(p5, v.y, acc8[5].y);
            acc8[6].x = fmaf(p6, v.x, acc8[6].x); acc8[6].y = fmaf(p6, v.y, acc8[6].y);
            acc8[7].x = fmaf(p7, v.x, acc8[7].x); acc8[7].y = fmaf(p7, v.y, acc8[7].y);
        }
        unsigned* an = a_bf + (size_t)n * 2048;
#pragma unroll
        for (int h = 0; h < 8; ++h)
            an[h * 256 + t] = (unsigned)f2bf(acc8[h].x) | ((unsigned)f2bf(acc8[h].y) << 16);
    }
}

// ------------------------------------------------- K10: LN(t1) mask + x residual
__global__ __launch_bounds__(256) void ln1_mask_add_k(
    const float* __restrict__ t1, const float* __restrict__ g,
    const float* __restrict__ be, const int* __restrict__ samples,
    const float* __restrict__ x, float* __restrict__ dec, unsigned* __restrict__ decb)
{
    __shared__ float red[4];
    const int n = blockIdx.x, t = threadIdx.x;
    float2 v = ((const float2*)(t1 + (size_t)n * DIM))[t];
    float mu  = blk_sum(v.x + v.y, red) * (1.f / DIM);
    float dx = v.x - mu, dy = v.y - mu;
    float var = blk_sum(dx * dx + dy * dy, red) * (1.f / DIM);
    float rs = rsqrtf(var + 1e-5f);
    float2 gg = ((const float2*)g)[t], bb = ((const float2*)be)[t];
    float sx = dx * rs * gg.x + bb.x, sy = dy * rs * gg.y + bb.y;
    if (samples[n] < 0) { sx = 0.f; sy = 0.f; }
    float2 xx = ((const float2*)(x + (size_t)n * DIM))[t];
    float ox = xx.x + sx, oy = xx.y + sy;
    ((float2*)(dec + (size_t)n * DIM))[t] = make_float2(ox, oy);
    decb[(size_t)n * 256 + t] = (unsigned)f2bf(ox) | ((unsigned)f2bf(oy) << 16);
}

// ---------------------------------------------------------------- launcher
extern "C" void kernel_launch(void* const* d_in, const int* in_sizes, int n_in,
                              void* d_out, int out_size, void* d_ws, size_t ws_size,
                              hipStream_t stream)
{
    const float* dec_output = (const float*)d_in[0];
    const float* mem_attn   = (const float*)d_in[1];
    const float* enc_mem    = (const float*)d_in[2];
    const float* temb_mem   = (const float*)d_in[3];
    const int*   mask_mem   = (const int*)d_in[4];
    const float* g0  = (const float*)d_in[6];
    const float* be0 = (const float*)d_in[7];
    const float* g1  = (const float*)d_in[8];
    const float* be1 = (const float*)d_in[9];
    const float* Wq  = (const float*)d_in[10];
    const float* bq  = (const float*)d_in[11];
    const float* Wk  = (const float*)d_in[12];
    const float* bk  = (const float*)d_in[13];
    const float* Wv  = (const float*)d_in[14];
    const float* bv  = (const float*)d_in[15];
    const float* Wo  = (const float*)d_in[16];
    const float* bo  = (const float*)d_in[17];
    const float* f1W1 = (const float*)d_in[18];
    const float* f1b1 = (const float*)d_in[19];
    const float* f1W2 = (const float*)d_in[20];
    const float* f1b2 = (const float*)d_in[21];
    const float* f2W1 = (const float*)d_in[22];
    const float* f2b1 = (const float*)d_in[23];
    const float* f2W2 = (const float*)d_in[24];
    const float* f2b2 = (const float*)d_in[25];
    float* out = (float*)d_out;

    float* ws = (float*)d_ws;
    float*          x_f   = ws + 0;                    // 524288
    unsigned*       x_b   = (unsigned*)(ws + 524288);  // 262144 f
    float*          qh_f  = ws + 786432;               // 524288
    unsigned short* qh_b  = (unsigned short*)(ws + 1310720); // 262144 f
    unsigned short* u_b   = (unsigned short*)(ws + 1572864); // 2097152 f
    unsigned short* a_b   = (unsigned short*)(ws + 3670016); // 2097152 f
    unsigned short* wqt   = (unsigned short*)(ws + 5767168);
    unsigned short* wkc   = (unsigned short*)(ws + 5898240);
    unsigned short* wvt   = (unsigned short*)(ws + 6029312);
    unsigned short* wot   = (unsigned short*)(ws + 6160384);
    unsigned short* f1w1t = (unsigned short*)(ws + 6291456);
    unsigned short* f1w2t = (unsigned short*)(ws + 6815744);
    unsigned short* f2w1t = (unsigned short*)(ws + 7340032);
    unsigned short* f2w2t = (unsigned short*)(ws + 7864320);
    int*            smp   = (int*)(ws + 8388608);
    float*          st0_f = (float*)u_b + 0;
    unsigned short* st0_b = (unsigned short*)((float*)u_b + 524288);
    float*          t1_f  = (float*)u_b + 786432;
    float*          dec_f = (float*)u_b + 1310720;
    unsigned*       dec_b = (unsigned*)((float*)u_b + 1835008);
    unsigned short* h1_b  = a_b;
    unsigned short* h2_b  = (unsigned short*)((float*)a_b + 1048576);

    PrepPtrs pp;
    pp.src[0] = Wq;   pp.dst[0] = wqt;
    pp.src[1] = Wk;   pp.dst[1] = wkc;
    pp.src[2] = Wv;   pp.dst[2] = wvt;
    pp.src[3] = Wo;   pp.dst[3] = wot;
    pp.src[4] = f1W1; pp.dst[4] = f1w1t;
    pp.src[5] = f1W2; pp.dst[5] = f1w2t;
    pp.src[6] = f2W1; pp.dst[6] = f2w1t;
    pp.src[7] = f2W2; pp.dst[7] = f2w2t;
    prep_weights_k<<<5120, 256, 0, stream>>>(pp);
    ln0_argmax_k<<<NQ, 256, 0, stream>>>(dec_output, mem_attn, g0, be0, x_f, x_b, smp);
    // QH = X @ Wq + bq
    mfma_gemm<false, true, false, true, true><<<dim3(8, 16, 1), 256, 0, stream>>>(
        (const unsigned short*)x_b, wqt, qh_f, qh_b, bq, nullptr,
        DIM, DIM, DIM, DIM, 0, 0, 0, 0);
    // U_h = QH_h @ Wk_h^T (batched heads, K=64)
    mfma_gemm<false, false, false, false, true><<<dim3(8, 16, NH), 256, 0, stream>>>(
        qh_b, wkc, nullptr, u_b, nullptr, nullptr,
        DHD, DIM, DIM, NH * DIM, DHD, DHD, DIM, 0);
    // scores -> softmax -> a (bf16)
    attn_mem_k<<<NQ, 256, 0, stream>>>(qh_f, u_b, enc_mem, temb_mem, mask_mem, smp,
                                       bk, (unsigned*)a_b);
    // CTX_h = A_h @ Wv_h + bv_h
    mfma_gemm<false, true, false, false, true><<<dim3(1, 16, NH), 256, 0, stream>>>(
        a_b, wvt, nullptr, qh_b, bv, nullptr,
        DIM, NH * DIM, DIM, DIM, DIM, DHD * DIM, DHD, DHD);
    // ST0 = X + CTX @ Wo + bo
    mfma_gemm<false, true, true, true, true><<<dim3(8, 16, 1), 256, 0, stream>>>(
        qh_b, wot, st0_f, st0_b, bo, x_f, DIM, DIM, DIM, DIM, 0, 0, 0, 0);
    // H1 = relu(ST0 @ f1W1 + f1b1)
    mfma_gemm<true, true, false, false, true><<<dim3(32, 16, 1), 256, 0, stream>>>(
        st0_b, f1w1t, nullptr, h1_b, f1b1, nullptr, DIM, DIM, DIM, DFF, 0, 0, 0, 0);
    // T1 = ST0 + H1 @ f1W2 + f1b2
    mfma_gemm<false, true, true, true, false><<<dim3(8, 16, 1), 256, 0, stream>>>(
        h1_b, f1w2t, t1_f, nullptr, f1b2, st0_f, DFF, DFF, DFF, DIM, 0, 0, 0, 0);
    // DEC = X + mask * LN1(T1)
    ln1_mask_add_k<<<NQ, 256, 0, stream>>>(t1_f, g1, be1, smp, x_f, dec_f, dec_b);
    // H2 = relu(DEC @ f2W1 + f2b1)
    mfma_gemm<true, true, false, false, true><<<dim3(32, 16, 1), 256, 0, stream>>>(
        (const unsigned short*)dec_b, f2w1t, nullptr, h2_b, f2b1, nullptr,
        DIM, DIM, DIM, DFF, 0, 0, 0, 0);
    // OUT = DEC + H2 @ f2W2 + f2b2
    mfma_gemm<false, true, true, true, false><<<dim3(8, 16, 1), 256, 0, stream>>>(
        h2_b, f2w2t, out, nullptr, f2b2, dec_f, DFF, DFF, DFF, DIM, 0, 0, 0, 0);

    (void)in_sizes; (void)n_in; (void)out_size; (void)ws_size;
}